// Round 3
// baseline (553.334 us; speedup 1.0000x reference)
//
#include <hip/hip_runtime.h>
#include <math.h>

typedef short bf16x8 __attribute__((ext_vector_type(8)));
typedef float f32x4 __attribute__((ext_vector_type(4)));
typedef unsigned short ushort8 __attribute__((ext_vector_type(8)));
typedef unsigned short ushort4v __attribute__((ext_vector_type(4)));

constexpr int R = 128, Cc = 256, E = 768, H = 12;
constexpr int M = R * Cc;                 // 32768 tokens
constexpr size_t TOK = (size_t)M * E;     // 25165824

// fp32 -> bf16 round-to-nearest-even
__device__ __forceinline__ unsigned short f2b(float f) {
  unsigned int u = __float_as_uint(f);
  u += 0x7fff + ((u >> 16) & 1);
  return (unsigned short)(u >> 16);
}

// async global->LDS, 16B per lane. LDS dest must be wave-uniform base + lane*16.
__device__ __forceinline__ void ldst16(const unsigned short* g, unsigned short* l) {
  __builtin_amdgcn_global_load_lds(
      (const __attribute__((address_space(1))) unsigned int*)g,
      (__attribute__((address_space(3))) unsigned int*)l, 16, 0, 0);
}

// ---------------------------------------------------------------------------
__global__ __launch_bounds__(256) void cvt_bf16(const float* __restrict__ in,
                                                unsigned short* __restrict__ out,
                                                int n8) {
  int i = blockIdx.x * 256 + threadIdx.x;
  if (i >= n8) return;
  const float4* p = (const float4*)in;
  float4 a = p[2 * i], b = p[2 * i + 1];
  ushort8 o;
  o[0] = f2b(a.x); o[1] = f2b(a.y); o[2] = f2b(a.z); o[3] = f2b(a.w);
  o[4] = f2b(b.x); o[5] = f2b(b.y); o[6] = f2b(b.z); o[7] = f2b(b.w);
  ((ushort8*)out)[i] = o;
}

// ---------------------------------------------------------------------------
// Shared 128x128-tile GEMM body: C_tile = A[128xK] * B[NxK]^T, BK=64.
// 256 thr = 4 waves (2x2 of 64x64). Each 64-K step: one stage (16KB A + 16KB B
// via global_load_lds width=16) + one barrier-pair + 32 MFMA/wave.
// BK=64 halves barrier/drain count vs BK=32 (m233: stage+drain is ~72% of the
// 2-phase critical path); 32KB LDS keeps 4 blocks/CU (VGPR-capped anyway).
// ---------------------------------------------------------------------------
__device__ __forceinline__ void gemm128(const unsigned short* __restrict__ A, int lda,
                                        const unsigned short* __restrict__ B, int ldb,
                                        int K, unsigned short* As, unsigned short* Bs,
                                        int wv, int ln, int wm, int wn,
                                        f32x4 (&acc)[4][4]) {
  const int srow = ln >> 3, scol = (ln & 7) * 8;  // 8 lanes x 16B per 128B row
  for (int k0 = 0; k0 < K; k0 += 64) {
    __syncthreads();
#pragma unroll
    for (int t = 0; t < 4; ++t) {
      const int ch = wv * 4 + t;       // 16 chunks of 1024B per 16KB tile
      const int row = ch * 8 + srow;
      ldst16(A + (size_t)row * lda + k0 + scol, As + ch * 512 + ln * 8);
      ldst16(B + (size_t)row * ldb + k0 + scol, Bs + ch * 512 + ln * 8);
    }
    __syncthreads();
#pragma unroll
    for (int dk = 0; dk < 2; ++dk) {
      bf16x8 a[4], b[4];
#pragma unroll
      for (int i = 0; i < 4; ++i)
        a[i] = *(const bf16x8*)(As + (wm + i * 16 + (ln & 15)) * 64 + dk * 32 + (ln >> 4) * 8);
#pragma unroll
      for (int j = 0; j < 4; ++j)
        b[j] = *(const bf16x8*)(Bs + (wn + j * 16 + (ln & 15)) * 64 + dk * 32 + (ln >> 4) * 8);
#pragma unroll
      for (int i = 0; i < 4; ++i)
#pragma unroll
        for (int j = 0; j < 4; ++j)
          acc[i][j] = __builtin_amdgcn_mfma_f32_16x16x32_bf16(a[i], b[j], acc[i][j], 0, 0, 0);
    }
  }
}

// ---------------------------------------------------------------------------
// Fused QKV projection: Y[m, 0:2304] = x[m,:] @ [Wq;Wk;Wv]^T + [bq;bk;bv]
// Epilogues write attention-friendly layouts:
//   q2[h][i][r*64+d]  (K-contiguous for QK^T, scaled)
//   k2[h][j][r*64+d]
//   v3[h][r*64+d][j]  (K-contiguous for PV)
// XCD-bijective swizzle: nwg=4608=8*576; same-m0 blocks stay on one XCD.
// ---------------------------------------------------------------------------
__global__ __launch_bounds__(256) void qkv_proj(
    const unsigned short* __restrict__ A, const unsigned short* __restrict__ B,
    const float* __restrict__ bq, const float* __restrict__ bk,
    const float* __restrict__ bv, unsigned short* __restrict__ q2,
    unsigned short* __restrict__ k2, unsigned short* __restrict__ v3, float scaling) {
  __shared__ unsigned short As[128 * 64];
  __shared__ unsigned short Bs[128 * 64];
  const int tid = threadIdx.x, wv = tid >> 6, ln = tid & 63;
  const unsigned p = blockIdx.x + blockIdx.y * 18;
  const unsigned l = (p & 7) * 576 + (p >> 3);
  const int bx = l % 18, by = l / 18;
  const int n0 = bx * 128, m0 = by * 128;
  const int wm = (wv & 1) * 64, wn = (wv >> 1) * 64;
  f32x4 acc[4][4] = {};
  gemm128(A + (size_t)m0 * 768, 768, B + (size_t)n0 * 768, 768, 768,
          As, Bs, wv, ln, wm, wn, acc);

  const int region = bx / 6;                       // 0=q, 1=k, 2=v (128 | 768)
  const float* bias = region == 0 ? bq : (region == 1 ? bk : bv);
  const float sc = region == 0 ? scaling : 1.0f;
  const int nq0 = n0 - region * 768;               // within-region base
#pragma unroll
  for (int j = 0; j < 4; ++j) {
    const int np = nq0 + wn + j * 16 + (ln & 15);  // [0,768): same h for 16-lane grp
    const int h = np >> 6, d = np & 63;
    const float bn = bias[np];
#pragma unroll
    for (int i = 0; i < 4; ++i) {
      const int mb = m0 + wm + i * 16 + (ln >> 4) * 4;  // token base, 4 consecutive
      if (region < 2) {
        unsigned short* dst = region == 0 ? q2 : k2;
#pragma unroll
        for (int r = 0; r < 4; ++r) {
          const int m = mb + r;
          const int ic = m & 255, rr = m >> 8;     // token = rr*256 + ic
          dst[(size_t)h * 2097152 + (size_t)ic * 8192 + rr * 64 + d] =
              f2b((acc[i][j][r] + bn) * sc);
        }
      } else {
        const int jc = mb & 255, rr = mb >> 8;     // 4 consecutive j-cols, same rr
        ushort4v o;
#pragma unroll
        for (int r = 0; r < 4; ++r) o[r] = f2b(acc[i][j][r] + bn);
        *(ushort4v*)(v3 + (size_t)h * 2097152 + ((size_t)rr * 64 + d) * 256 + jc) = o;
      }
    }
  }
}

// ---------------------------------------------------------------------------
// QK^T: per head, S[i,j] = sum_{rd} q2[h][i][rd] * k2[h][j][rd]; K=8192 split 8x.
// grid (4, 12, 8): bx -> 2x2 (i,j) 128-tiles, y = head, z = K-chunk of 1024.
// ---------------------------------------------------------------------------
__global__ __launch_bounds__(256) void qk_gemm(const unsigned short* __restrict__ q2,
                                               const unsigned short* __restrict__ k2,
                                               float* __restrict__ Sp) {
  __shared__ unsigned short As[128 * 64];
  __shared__ unsigned short Bs[128 * 64];
  const int tid = threadIdx.x, wv = tid >> 6, ln = tid & 63;
  const int i0 = (blockIdx.x & 1) * 128, j0 = (blockIdx.x >> 1) * 128;
  const int h = blockIdx.y, kc = blockIdx.z;
  const int wm = (wv & 1) * 64, wn = (wv >> 1) * 64;
  f32x4 acc[4][4] = {};
  const unsigned short* Ap = q2 + (size_t)h * 2097152 + (size_t)i0 * 8192 + kc * 1024;
  const unsigned short* Bp = k2 + (size_t)h * 2097152 + (size_t)j0 * 8192 + kc * 1024;
  gemm128(Ap, 8192, Bp, 8192, 1024, As, Bs, wv, ln, wm, wn, acc);
  float* out = Sp + ((size_t)kc * H + h) * 65536;
#pragma unroll
  for (int j = 0; j < 4; ++j) {
    const int jj = j0 + wn + j * 16 + (ln & 15);
#pragma unroll
    for (int i = 0; i < 4; ++i)
#pragma unroll
      for (int r = 0; r < 4; ++r) {
        const int ii = i0 + wm + i * 16 + (ln >> 4) * 4 + r;
        out[(size_t)ii * 256 + jj] = acc[i][j][r];
      }
  }
}

// ---------------------------------------------------------------------------
// Sum 8 K-partials, softmax over j, write fp32 probs (d_out) + bf16 copy (ws).
// ---------------------------------------------------------------------------
__global__ __launch_bounds__(256) void softmax_k(const float* __restrict__ Sp,
                                                 float* __restrict__ P,
                                                 unsigned short* __restrict__ Pb) {
  const int row = blockIdx.x, j = threadIdx.x;  // row = h*C + i
  const size_t stride = (size_t)H * Cc * Cc;    // 786432
  const size_t base = (size_t)row * Cc + j;
  float s = 0.f;
#pragma unroll
  for (int c = 0; c < 8; ++c) s += Sp[base + c * stride];
  float m = s;
#pragma unroll
  for (int o = 32; o > 0; o >>= 1) m = fmaxf(m, __shfl_xor(m, o));
  __shared__ float sm[4], ss[4];
  const int wid = j >> 6, lane = j & 63;
  if (lane == 0) sm[wid] = m;
  __syncthreads();
  m = fmaxf(fmaxf(sm[0], sm[1]), fmaxf(sm[2], sm[3]));
  float e = expf(s - m);
  float t = e;
#pragma unroll
  for (int o = 32; o > 0; o >>= 1) t += __shfl_xor(t, o);
  if (lane == 0) ss[wid] = t;
  __syncthreads();
  t = ss[0] + ss[1] + ss[2] + ss[3];
  const float p = e / t;
  P[base] = p;
  Pb[base] = f2b(p);
}

// ---------------------------------------------------------------------------
// PV: per head, C2[i][rd] = sum_j P[h][i][j] * v3[h][rd][j]  (M=256,N=8192,K=256)
// grid (128, 12): bx -> 2 (i) x 64 (rd) 128-tiles, y = head. Epilogue scatters
// straight to token layout Co[(r*256+i)*768 + h*64 + d] for the O-projection.
// XCD swizzle keeps the i-pair (shared v3 panel) on one XCD.
// ---------------------------------------------------------------------------
__global__ __launch_bounds__(256) void pv_gemm(const unsigned short* __restrict__ P,
                                               const unsigned short* __restrict__ V,
                                               unsigned short* __restrict__ Co) {
  __shared__ unsigned short As[128 * 64];
  __shared__ unsigned short Bs[128 * 64];
  const int tid = threadIdx.x, wv = tid >> 6, ln = tid & 63;
  const unsigned p = blockIdx.x + blockIdx.y * 128;
  const unsigned l = (p & 7) * 192 + (p >> 3);     // nwg = 1536 = 8*192
  const int bx = l & 127, h = l >> 7;
  const int i0 = (bx & 1) * 128, n0 = (bx >> 1) * 128;
  const int wm = (wv & 1) * 64, wn = (wv >> 1) * 64;
  f32x4 acc[4][4] = {};
  const unsigned short* Ap = P + (size_t)h * 65536 + (size_t)i0 * 256;
  const unsigned short* Bp = V + (size_t)h * 2097152 + (size_t)n0 * 256;
  gemm128(Ap, 256, Bp, 256, 256, As, Bs, wv, ln, wm, wn, acc);
#pragma unroll
  for (int j = 0; j < 4; ++j) {
    const int n = n0 + wn + j * 16 + (ln & 15);    // rd; same rr for 16-lane grp
    const int rr = n >> 6, d = n & 63;
#pragma unroll
    for (int i = 0; i < 4; ++i)
#pragma unroll
      for (int r = 0; r < 4; ++r) {
        const int ii = i0 + wm + i * 16 + (ln >> 4) * 4 + r;
        Co[((size_t)rr * 256 + ii) * 768 + h * 64 + d] = f2b(acc[i][j][r]);
      }
  }
}

// ---------------------------------------------------------------------------
// Output projection: out = Co @ Wo^T + bo (fp32 out), XCD-swizzled.
// ---------------------------------------------------------------------------
__global__ __launch_bounds__(256) void o_proj(const unsigned short* __restrict__ A,
                                              const unsigned short* __restrict__ B,
                                              const float* __restrict__ bias,
                                              float* __restrict__ Y) {
  __shared__ unsigned short As[128 * 64];
  __shared__ unsigned short Bs[128 * 64];
  const int tid = threadIdx.x, wv = tid >> 6, ln = tid & 63;
  const unsigned p = blockIdx.x + blockIdx.y * 6;
  const unsigned l = (p & 7) * 192 + (p >> 3);     // nwg = 1536 = 8*192
  const int bx = l % 6, by = l / 6;
  const int n0 = bx * 128, m0 = by * 128;
  const int wm = (wv & 1) * 64, wn = (wv >> 1) * 64;
  f32x4 acc[4][4] = {};
  gemm128(A + (size_t)m0 * 768, 768, B + (size_t)n0 * 768, 768, 768,
          As, Bs, wv, ln, wm, wn, acc);
#pragma unroll
  for (int j = 0; j < 4; ++j) {
    const int n = n0 + wn + j * 16 + (ln & 15);
    const float bn = bias[n];
#pragma unroll
    for (int i = 0; i < 4; ++i)
#pragma unroll
      for (int r = 0; r < 4; ++r) {
        const int m = m0 + wm + i * 16 + (ln >> 4) * 4 + r;
        Y[(size_t)m * 768 + n] = acc[i][j][r] + bn;
      }
  }
}

// ---------------------------------------------------------------------------
extern "C" void kernel_launch(void* const* d_in, const int* in_sizes, int n_in,
                              void* d_out, int out_size, void* d_ws, size_t ws_size,
                              hipStream_t stream) {
  const float* x  = (const float*)d_in[0];
  const float* Wq = (const float*)d_in[1];
  const float* bq = (const float*)d_in[2];
  const float* Wk = (const float*)d_in[3];
  const float* bk = (const float*)d_in[4];
  const float* Wv = (const float*)d_in[5];
  const float* bv = (const float*)d_in[6];
  const float* Wo = (const float*)d_in[7];
  const float* bo = (const float*)d_in[8];
  float* out = (float*)d_out;             // (R,C,1,E)
  float* probs = out + TOK;               // (H,1,C,C)

  char* ws = (char*)d_ws;
  unsigned short* x_bf  = (unsigned short*)(ws);              // 50.3 MB (dead after qkv_proj)
  unsigned short* q2    = (unsigned short*)(ws + 50331648);   // 50.3 MB [h][i][rd]
  unsigned short* k2    = (unsigned short*)(ws + 100663296);  // 50.3 MB [h][j][rd]
  unsigned short* v3    = (unsigned short*)(ws + 150994944);  // 50.3 MB [h][rd][j]
  unsigned short* Wq_bf = (unsigned short*)(ws + 201326592);  // 4 x 1.18 MB (contiguous!)
  unsigned short* Wk_bf = Wq_bf + 589824;
  unsigned short* Wv_bf = Wk_bf + 589824;
  unsigned short* Wo_bf = Wv_bf + 589824;
  // aliases into dead x_bf region:
  float* S_part         = (float*)(ws);                       // 8 x 3.15 MB = 25.2 MB
  unsigned short* P_bf  = (unsigned short*)(ws + 25165824);   // 1.6 MB
  unsigned short* c_bf  = q2;  // q2 dead after qk_gemm

  const float scaling = 0.125f / sqrtf(128.f);  // Dk^-0.5 / sqrt(R)

  cvt_bf16<<<12288, 256, 0, stream>>>(x, x_bf, 3145728);
  cvt_bf16<<<288, 256, 0, stream>>>(Wq, Wq_bf, 73728);
  cvt_bf16<<<288, 256, 0, stream>>>(Wk, Wk_bf, 73728);
  cvt_bf16<<<288, 256, 0, stream>>>(Wv, Wv_bf, 73728);
  cvt_bf16<<<288, 256, 0, stream>>>(Wo, Wo_bf, 73728);

  // Fused QKV: N = 2304 (Wq,Wk,Wv contiguous rows), x fetched once.
  qkv_proj<<<dim3(18, 256), 256, 0, stream>>>(x_bf, Wq_bf, bq, bk, bv,
                                              q2, k2, v3, scaling);

  qk_gemm<<<dim3(4, H, 8), 256, 0, stream>>>(q2, k2, S_part);
  softmax_k<<<H * Cc, 256, 0, stream>>>(S_part, probs, P_bf);
  pv_gemm<<<dim3(128, H), 256, 0, stream>>>(P_bf, v3, c_bf);

  o_proj<<<dim3(6, 256), 256, 0, stream>>>(c_bf, Wo_bf, bo, out);
}

// Round 4
// 537.521 us; speedup vs baseline: 1.0294x; 1.0294x over previous
//
#include <hip/hip_runtime.h>
#include <math.h>

typedef short bf16x8 __attribute__((ext_vector_type(8)));
typedef float f32x4 __attribute__((ext_vector_type(4)));
typedef unsigned short ushort8 __attribute__((ext_vector_type(8)));
typedef unsigned short ushort4v __attribute__((ext_vector_type(4)));

constexpr int R = 128, Cc = 256, E = 768, H = 12;
constexpr int M = R * Cc;                 // 32768 tokens
constexpr size_t TOK = (size_t)M * E;     // 25165824

// fp32 -> bf16 round-to-nearest-even
__device__ __forceinline__ unsigned short f2b(float f) {
  unsigned int u = __float_as_uint(f);
  u += 0x7fff + ((u >> 16) & 1);
  return (unsigned short)(u >> 16);
}

// async global->LDS, 16B per lane. LDS dest must be wave-uniform base + lane*16.
__device__ __forceinline__ void ldst16(const unsigned short* g, unsigned short* l) {
  __builtin_amdgcn_global_load_lds(
      (const __attribute__((address_space(1))) unsigned int*)g,
      (__attribute__((address_space(3))) unsigned int*)l, 16, 0, 0);
}

// ---------------------------------------------------------------------------
__global__ __launch_bounds__(256) void cvt_bf16(const float* __restrict__ in,
                                                unsigned short* __restrict__ out,
                                                int n8) {
  int i = blockIdx.x * 256 + threadIdx.x;
  if (i >= n8) return;
  const float4* p = (const float4*)in;
  float4 a = p[2 * i], b = p[2 * i + 1];
  ushort8 o;
  o[0] = f2b(a.x); o[1] = f2b(a.y); o[2] = f2b(a.z); o[3] = f2b(a.w);
  o[4] = f2b(b.x); o[5] = f2b(b.y); o[6] = f2b(b.z); o[7] = f2b(b.w);
  ((ushort8*)out)[i] = o;
}

// ---------------------------------------------------------------------------
// Shared 128x128-tile GEMM body, BK=64, double-buffered prefetch + XOR swizzle.
//  - LDS dest is linear (global_load_lds constraint); bank swizzle is applied by
//    permuting the per-lane GLOBAL source chunk (rule #21: both-sides-or-neither).
//    LDS(row, chunk c) holds global chunk c ^ (row&7); each 8-lane row group
//    still covers one contiguous 128B segment (coalescing preserved).
//  - ds_read applies the same involution -> 8 rows spread over 8 16B slots:
//    bank-balanced (2-way max, free per m136). Fixes the measured 16-way
//    conflict (42.5M cycles, ~27% of qkv time at BK=64 linear).
//  - T3-minimum pipeline: stage tile t+1 into buf[cur^1] BEFORE computing tile
//    t from buf[cur]; ONE __syncthreads per K-step (its implicit vmcnt(0)+
//    lgkmcnt(0) drain orders both the prefetch writes and the ds_reads).
//    HBM latency overlaps the 32-MFMA compute phase instead of being exposed.
//  - LDS 64KB -> 2 blocks/CU; fine since the block self-hides latency.
// ---------------------------------------------------------------------------
__device__ __forceinline__ void stage64(const unsigned short* __restrict__ A, int lda,
                                        const unsigned short* __restrict__ B, int ldb,
                                        int k0, unsigned short* As, unsigned short* Bs,
                                        int wv, int ln, int srow, int scol) {
#pragma unroll
  for (int t = 0; t < 4; ++t) {
    const int ch = wv * 4 + t;           // 16 chunks of 1024B per 16KB tile
    const int row = ch * 8 + srow;
    ldst16(A + (size_t)row * lda + k0 + scol, As + ch * 512 + ln * 8);
    ldst16(B + (size_t)row * ldb + k0 + scol, Bs + ch * 512 + ln * 8);
  }
}

__device__ __forceinline__ void gemm128(const unsigned short* __restrict__ A, int lda,
                                        const unsigned short* __restrict__ B, int ldb,
                                        int K, unsigned short* As, unsigned short* Bs,
                                        int wv, int ln, int wm, int wn,
                                        f32x4 (&acc)[4][4]) {
  const int srow = ln >> 3;                       // 8 lanes x 16B per 128B row
  const int scol = ((ln & 7) ^ srow) * 8;         // pre-swizzled source chunk
  stage64(A, lda, B, ldb, 0, As, Bs, wv, ln, srow, scol);
  __syncthreads();
  int cur = 0;
  for (int k0 = 0; k0 < K; k0 += 64) {
    if (k0 + 64 < K)
      stage64(A, lda, B, ldb, k0 + 64, As + (cur ^ 1) * 8192, Bs + (cur ^ 1) * 8192,
              wv, ln, srow, scol);
    const unsigned short* Ab = As + cur * 8192;
    const unsigned short* Bb = Bs + cur * 8192;
#pragma unroll
    for (int dk = 0; dk < 2; ++dk) {
      const int rc = ((dk * 4 + (ln >> 4)) ^ (ln & 7)) * 8;  // swizzled read chunk
      bf16x8 a[4], b[4];
#pragma unroll
      for (int i = 0; i < 4; ++i)
        a[i] = *(const bf16x8*)(Ab + (wm + i * 16 + (ln & 15)) * 64 + rc);
#pragma unroll
      for (int j = 0; j < 4; ++j)
        b[j] = *(const bf16x8*)(Bb + (wn + j * 16 + (ln & 15)) * 64 + rc);
#pragma unroll
      for (int i = 0; i < 4; ++i)
#pragma unroll
        for (int j = 0; j < 4; ++j)
          acc[i][j] = __builtin_amdgcn_mfma_f32_16x16x32_bf16(a[i], b[j], acc[i][j], 0, 0, 0);
    }
    __syncthreads();   // drains prefetch (vmcnt) + ds_reads (lgkm); buf swap safe
    cur ^= 1;
  }
}

// ---------------------------------------------------------------------------
// Fused QKV projection: Y[m, 0:2304] = x[m,:] @ [Wq;Wk;Wv]^T + [bq;bk;bv]
// Epilogues write attention-friendly layouts:
//   q2[h][i][r*64+d]  (K-contiguous for QK^T, scaled)
//   k2[h][j][r*64+d]
//   v3[h][r*64+d][j]  (K-contiguous for PV)
// XCD-bijective swizzle: nwg=4608=8*576; same-m0 blocks stay on one XCD.
// ---------------------------------------------------------------------------
__global__ __launch_bounds__(256) void qkv_proj(
    const unsigned short* __restrict__ A, const unsigned short* __restrict__ B,
    const float* __restrict__ bq, const float* __restrict__ bk,
    const float* __restrict__ bv, unsigned short* __restrict__ q2,
    unsigned short* __restrict__ k2, unsigned short* __restrict__ v3, float scaling) {
  __shared__ unsigned short As[2 * 128 * 64];
  __shared__ unsigned short Bs[2 * 128 * 64];
  const int tid = threadIdx.x, wv = tid >> 6, ln = tid & 63;
  const unsigned p = blockIdx.x + blockIdx.y * 18;
  const unsigned l = (p & 7) * 576 + (p >> 3);
  const int bx = l % 18, by = l / 18;
  const int n0 = bx * 128, m0 = by * 128;
  const int wm = (wv & 1) * 64, wn = (wv >> 1) * 64;
  f32x4 acc[4][4] = {};
  gemm128(A + (size_t)m0 * 768, 768, B + (size_t)n0 * 768, 768, 768,
          As, Bs, wv, ln, wm, wn, acc);

  const int region = bx / 6;                       // 0=q, 1=k, 2=v (128 | 768)
  const float* bias = region == 0 ? bq : (region == 1 ? bk : bv);
  const float sc = region == 0 ? scaling : 1.0f;
  const int nq0 = n0 - region * 768;               // within-region base
#pragma unroll
  for (int j = 0; j < 4; ++j) {
    const int np = nq0 + wn + j * 16 + (ln & 15);  // [0,768): same h for 16-lane grp
    const int h = np >> 6, d = np & 63;
    const float bn = bias[np];
#pragma unroll
    for (int i = 0; i < 4; ++i) {
      const int mb = m0 + wm + i * 16 + (ln >> 4) * 4;  // token base, 4 consecutive
      if (region < 2) {
        unsigned short* dst = region == 0 ? q2 : k2;
#pragma unroll
        for (int r = 0; r < 4; ++r) {
          const int m = mb + r;
          const int ic = m & 255, rr = m >> 8;     // token = rr*256 + ic
          dst[(size_t)h * 2097152 + (size_t)ic * 8192 + rr * 64 + d] =
              f2b((acc[i][j][r] + bn) * sc);
        }
      } else {
        const int jc = mb & 255, rr = mb >> 8;     // 4 consecutive j-cols, same rr
        ushort4v o;
#pragma unroll
        for (int r = 0; r < 4; ++r) o[r] = f2b(acc[i][j][r] + bn);
        *(ushort4v*)(v3 + (size_t)h * 2097152 + ((size_t)rr * 64 + d) * 256 + jc) = o;
      }
    }
  }
}

// ---------------------------------------------------------------------------
// QK^T: per head, S[i,j] = sum_{rd} q2[h][i][rd] * k2[h][j][rd]; K=8192 split 8x.
// grid (4, 12, 8): bx -> 2x2 (i,j) 128-tiles, y = head, z = K-chunk of 1024.
// ---------------------------------------------------------------------------
__global__ __launch_bounds__(256) void qk_gemm(const unsigned short* __restrict__ q2,
                                               const unsigned short* __restrict__ k2,
                                               float* __restrict__ Sp) {
  __shared__ unsigned short As[2 * 128 * 64];
  __shared__ unsigned short Bs[2 * 128 * 64];
  const int tid = threadIdx.x, wv = tid >> 6, ln = tid & 63;
  const int i0 = (blockIdx.x & 1) * 128, j0 = (blockIdx.x >> 1) * 128;
  const int h = blockIdx.y, kc = blockIdx.z;
  const int wm = (wv & 1) * 64, wn = (wv >> 1) * 64;
  f32x4 acc[4][4] = {};
  const unsigned short* Ap = q2 + (size_t)h * 2097152 + (size_t)i0 * 8192 + kc * 1024;
  const unsigned short* Bp = k2 + (size_t)h * 2097152 + (size_t)j0 * 8192 + kc * 1024;
  gemm128(Ap, 8192, Bp, 8192, 1024, As, Bs, wv, ln, wm, wn, acc);
  float* out = Sp + ((size_t)kc * H + h) * 65536;
#pragma unroll
  for (int j = 0; j < 4; ++j) {
    const int jj = j0 + wn + j * 16 + (ln & 15);
#pragma unroll
    for (int i = 0; i < 4; ++i)
#pragma unroll
      for (int r = 0; r < 4; ++r) {
        const int ii = i0 + wm + i * 16 + (ln >> 4) * 4 + r;
        out[(size_t)ii * 256 + jj] = acc[i][j][r];
      }
  }
}

// ---------------------------------------------------------------------------
// Sum 8 K-partials, softmax over j, write fp32 probs (d_out) + bf16 copy (ws).
// ---------------------------------------------------------------------------
__global__ __launch_bounds__(256) void softmax_k(const float* __restrict__ Sp,
                                                 float* __restrict__ P,
                                                 unsigned short* __restrict__ Pb) {
  const int row = blockIdx.x, j = threadIdx.x;  // row = h*C + i
  const size_t stride = (size_t)H * Cc * Cc;    // 786432
  const size_t base = (size_t)row * Cc + j;
  float s = 0.f;
#pragma unroll
  for (int c = 0; c < 8; ++c) s += Sp[base + c * stride];
  float m = s;
#pragma unroll
  for (int o = 32; o > 0; o >>= 1) m = fmaxf(m, __shfl_xor(m, o));
  __shared__ float sm[4], ss[4];
  const int wid = j >> 6, lane = j & 63;
  if (lane == 0) sm[wid] = m;
  __syncthreads();
  m = fmaxf(fmaxf(sm[0], sm[1]), fmaxf(sm[2], sm[3]));
  float e = expf(s - m);
  float t = e;
#pragma unroll
  for (int o = 32; o > 0; o >>= 1) t += __shfl_xor(t, o);
  if (lane == 0) ss[wid] = t;
  __syncthreads();
  t = ss[0] + ss[1] + ss[2] + ss[3];
  const float p = e / t;
  P[base] = p;
  Pb[base] = f2b(p);
}

// ---------------------------------------------------------------------------
// PV: per head, C2[i][rd] = sum_j P[h][i][j] * v3[h][rd][j]  (M=256,N=8192,K=256)
// grid (128, 12): bx -> 2 (i) x 64 (rd) 128-tiles, y = head. Epilogue scatters
// straight to token layout Co[(r*256+i)*768 + h*64 + d] for the O-projection.
// ---------------------------------------------------------------------------
__global__ __launch_bounds__(256) void pv_gemm(const unsigned short* __restrict__ P,
                                               const unsigned short* __restrict__ V,
                                               unsigned short* __restrict__ Co) {
  __shared__ unsigned short As[2 * 128 * 64];
  __shared__ unsigned short Bs[2 * 128 * 64];
  const int tid = threadIdx.x, wv = tid >> 6, ln = tid & 63;
  const unsigned p = blockIdx.x + blockIdx.y * 128;
  const unsigned l = (p & 7) * 192 + (p >> 3);     // nwg = 1536 = 8*192
  const int bx = l & 127, h = l >> 7;
  const int i0 = (bx & 1) * 128, n0 = (bx >> 1) * 128;
  const int wm = (wv & 1) * 64, wn = (wv >> 1) * 64;
  f32x4 acc[4][4] = {};
  const unsigned short* Ap = P + (size_t)h * 65536 + (size_t)i0 * 256;
  const unsigned short* Bp = V + (size_t)h * 2097152 + (size_t)n0 * 256;
  gemm128(Ap, 256, Bp, 256, 256, As, Bs, wv, ln, wm, wn, acc);
#pragma unroll
  for (int j = 0; j < 4; ++j) {
    const int n = n0 + wn + j * 16 + (ln & 15);    // rd; same rr for 16-lane grp
    const int rr = n >> 6, d = n & 63;
#pragma unroll
    for (int i = 0; i < 4; ++i)
#pragma unroll
      for (int r = 0; r < 4; ++r) {
        const int ii = i0 + wm + i * 16 + (ln >> 4) * 4 + r;
        Co[((size_t)rr * 256 + ii) * 768 + h * 64 + d] = f2b(acc[i][j][r]);
      }
  }
}

// ---------------------------------------------------------------------------
// Output projection: out = Co @ Wo^T + bo (fp32 out), XCD-swizzled.
// ---------------------------------------------------------------------------
__global__ __launch_bounds__(256) void o_proj(const unsigned short* __restrict__ A,
                                              const unsigned short* __restrict__ B,
                                              const float* __restrict__ bias,
                                              float* __restrict__ Y) {
  __shared__ unsigned short As[2 * 128 * 64];
  __shared__ unsigned short Bs[2 * 128 * 64];
  const int tid = threadIdx.x, wv = tid >> 6, ln = tid & 63;
  const unsigned p = blockIdx.x + blockIdx.y * 6;
  const unsigned l = (p & 7) * 192 + (p >> 3);     // nwg = 1536 = 8*192
  const int bx = l % 6, by = l / 6;
  const int n0 = bx * 128, m0 = by * 128;
  const int wm = (wv & 1) * 64, wn = (wv >> 1) * 64;
  f32x4 acc[4][4] = {};
  gemm128(A + (size_t)m0 * 768, 768, B + (size_t)n0 * 768, 768, 768,
          As, Bs, wv, ln, wm, wn, acc);
#pragma unroll
  for (int j = 0; j < 4; ++j) {
    const int n = n0 + wn + j * 16 + (ln & 15);
    const float bn = bias[n];
#pragma unroll
    for (int i = 0; i < 4; ++i)
#pragma unroll
      for (int r = 0; r < 4; ++r) {
        const int m = m0 + wm + i * 16 + (ln >> 4) * 4 + r;
        Y[(size_t)m * 768 + n] = acc[i][j][r] + bn;
      }
  }
}

// ---------------------------------------------------------------------------
extern "C" void kernel_launch(void* const* d_in, const int* in_sizes, int n_in,
                              void* d_out, int out_size, void* d_ws, size_t ws_size,
                              hipStream_t stream) {
  const float* x  = (const float*)d_in[0];
  const float* Wq = (const float*)d_in[1];
  const float* bq = (const float*)d_in[2];
  const float* Wk = (const float*)d_in[3];
  const float* bk = (const float*)d_in[4];
  const float* Wv = (const float*)d_in[5];
  const float* bv = (const float*)d_in[6];
  const float* Wo = (const float*)d_in[7];
  const float* bo = (const float*)d_in[8];
  float* out = (float*)d_out;             // (R,C,1,E)
  float* probs = out + TOK;               // (H,1,C,C)

  char* ws = (char*)d_ws;
  unsigned short* x_bf  = (unsigned short*)(ws);              // 50.3 MB (dead after qkv_proj)
  unsigned short* q2    = (unsigned short*)(ws + 50331648);   // 50.3 MB [h][i][rd]
  unsigned short* k2    = (unsigned short*)(ws + 100663296);  // 50.3 MB [h][j][rd]
  unsigned short* v3    = (unsigned short*)(ws + 150994944);  // 50.3 MB [h][rd][j]
  unsigned short* Wq_bf = (unsigned short*)(ws + 201326592);  // 4 x 1.18 MB (contiguous!)
  unsigned short* Wk_bf = Wq_bf + 589824;
  unsigned short* Wv_bf = Wk_bf + 589824;
  unsigned short* Wo_bf = Wv_bf + 589824;
  // aliases into dead x_bf region:
  float* S_part         = (float*)(ws);                       // 8 x 3.15 MB = 25.2 MB
  unsigned short* P_bf  = (unsigned short*)(ws + 25165824);   // 1.6 MB
  unsigned short* c_bf  = q2;  // q2 dead after qk_gemm

  const float scaling = 0.125f / sqrtf(128.f);  // Dk^-0.5 / sqrt(R)

  cvt_bf16<<<12288, 256, 0, stream>>>(x, x_bf, 3145728);
  cvt_bf16<<<288, 256, 0, stream>>>(Wq, Wq_bf, 73728);
  cvt_bf16<<<288, 256, 0, stream>>>(Wk, Wk_bf, 73728);
  cvt_bf16<<<288, 256, 0, stream>>>(Wv, Wv_bf, 73728);
  cvt_bf16<<<288, 256, 0, stream>>>(Wo, Wo_bf, 73728);

  // Fused QKV: N = 2304 (Wq,Wk,Wv contiguous rows), x fetched once.
  qkv_proj<<<dim3(18, 256), 256, 0, stream>>>(x_bf, Wq_bf, bq, bk, bv,
                                              q2, k2, v3, scaling);

  qk_gemm<<<dim3(4, H, 8), 256, 0, stream>>>(q2, k2, S_part);
  softmax_k<<<H * Cc, 256, 0, stream>>>(S_part, probs, P_bf);
  pv_gemm<<<dim3(128, H), 256, 0, stream>>>(P_bf, v3, c_bf);

  o_proj<<<dim3(6, 256), 256, 0, stream>>>(c_bf, Wo_bf, bo, out);
}

// Round 5
// 492.091 us; speedup vs baseline: 1.1245x; 1.0923x over previous
//
#include <hip/hip_runtime.h>
#include <math.h>

typedef short bf16x8 __attribute__((ext_vector_type(8)));
typedef float f32x4 __attribute__((ext_vector_type(4)));
typedef unsigned short ushort8 __attribute__((ext_vector_type(8)));
typedef unsigned short ushort4v __attribute__((ext_vector_type(4)));

constexpr int R = 128, Cc = 256, E = 768, H = 12;
constexpr int M = R * Cc;                 // 32768 tokens
constexpr size_t TOK = (size_t)M * E;     // 25165824

// fp32 -> bf16 round-to-nearest-even
__device__ __forceinline__ unsigned short f2b(float f) {
  unsigned int u = __float_as_uint(f);
  u += 0x7fff + ((u >> 16) & 1);
  return (unsigned short)(u >> 16);
}

// async global->LDS, 16B per lane. LDS dest must be wave-uniform base + lane*16.
__device__ __forceinline__ void ldst16(const unsigned short* g, unsigned short* l) {
  __builtin_amdgcn_global_load_lds(
      (const __attribute__((address_space(1))) unsigned int*)g,
      (__attribute__((address_space(3))) unsigned int*)l, 16, 0, 0);
}

// ---------------------------------------------------------------------------
__global__ __launch_bounds__(256) void cvt_bf16(const float* __restrict__ in,
                                                unsigned short* __restrict__ out,
                                                int n8) {
  int i = blockIdx.x * 256 + threadIdx.x;
  if (i >= n8) return;
  const float4* p = (const float4*)in;
  float4 a = p[2 * i], b = p[2 * i + 1];
  ushort8 o;
  o[0] = f2b(a.x); o[1] = f2b(a.y); o[2] = f2b(a.z); o[3] = f2b(a.w);
  o[4] = f2b(b.x); o[5] = f2b(b.y); o[6] = f2b(b.z); o[7] = f2b(b.w);
  ((ushort8*)out)[i] = o;
}

// ---------------------------------------------------------------------------
// Shared 128x128-tile GEMM body, BK=64, XOR-swizzled LDS, COUNTED-vmcnt pipeline.
// R4 post-mortem: drain-0 dbuf left MfmaUtil at 21% (2-phase plateau, m233);
// m218 isolates counted-vmcnt as the missing lever (+38-73%).
// Schedule per K-step t (2 LDS buffers, prefetch depth 2):
//   vmcnt(8|0) + barrier   -> buf[t&1] valid collectively (per-wave count, then
//                             barrier makes it collective; stage t+1 stays in flight)
//   ds_read 16 frags->regs (swizzled; conflicts=0 measured R4)
//   lgkmcnt(0) + sched_barrier + barrier -> all waves' reads retired
//   STAGE(t+2 -> buf[t&1]) -> 8 loads issued, NOT drained this step
//   64 MFMA from regs       -> overlaps the in-flight loads
// Swizzle (rule #21, both-sides): LDS stays linear for global_load_lds; the
// per-lane GLOBAL source chunk is permuted (scol), ds_read applies the same
// involution (rc). Each 8-lane row group still covers one contiguous 128B
// segment -> coalescing preserved.
// ---------------------------------------------------------------------------
__device__ __forceinline__ void stage64(const unsigned short* __restrict__ A, int lda,
                                        const unsigned short* __restrict__ B, int ldb,
                                        int k0, unsigned short* As, unsigned short* Bs,
                                        int wv, int ln, int srow, int scol) {
#pragma unroll
  for (int t = 0; t < 4; ++t) {
    const int ch = wv * 4 + t;           // 16 chunks of 1024B per 16KB tile
    const int row = ch * 8 + srow;
    ldst16(A + (size_t)row * lda + k0 + scol, As + ch * 512 + ln * 8);
    ldst16(B + (size_t)row * ldb + k0 + scol, Bs + ch * 512 + ln * 8);
  }
}

__device__ __forceinline__ void gemm128(const unsigned short* __restrict__ A, int lda,
                                        const unsigned short* __restrict__ B, int ldb,
                                        int K, unsigned short* As, unsigned short* Bs,
                                        int wv, int ln, int wm, int wn,
                                        f32x4 (&acc)[4][4]) {
  const int srow = ln >> 3;                       // 8 lanes x 16B per 128B row
  const int scol = ((ln & 7) ^ srow) * 8;         // pre-swizzled source chunk
  const int nt = K >> 6;
  stage64(A, lda, B, ldb, 0, As, Bs, wv, ln, srow, scol);
  if (nt > 1)
    stage64(A, lda, B, ldb, 64, As + 8192, Bs + 8192, wv, ln, srow, scol);
  for (int t = 0; t < nt; ++t) {
    const int cur = t & 1;
    // (a) my stage-t loads done (8 of stage t+1 may stay in flight); barrier
    //     makes the per-wave guarantee collective -> buf[cur] fully valid.
    if (t + 1 < nt) {
      asm volatile("s_waitcnt vmcnt(8)" ::: "memory");
    } else {
      asm volatile("s_waitcnt vmcnt(0)" ::: "memory");
    }
    __builtin_amdgcn_sched_barrier(0);
    __builtin_amdgcn_s_barrier();
    const unsigned short* Ab = As + cur * 8192;
    const unsigned short* Bb = Bs + cur * 8192;
    bf16x8 a[2][4], b[2][4];
#pragma unroll
    for (int dk = 0; dk < 2; ++dk) {
      const int rc = ((dk * 4 + (ln >> 4)) ^ (ln & 7)) * 8;  // swizzled read chunk
#pragma unroll
      for (int i = 0; i < 4; ++i)
        a[dk][i] = *(const bf16x8*)(Ab + (wm + i * 16 + (ln & 15)) * 64 + rc);
#pragma unroll
      for (int j = 0; j < 4; ++j)
        b[dk][j] = *(const bf16x8*)(Bb + (wn + j * 16 + (ln & 15)) * 64 + rc);
    }
    // (b) all my ds_reads retired into regs; barrier -> ALL waves done reading
    //     buf[cur]; safe to overwrite it with stage t+2.
    asm volatile("s_waitcnt lgkmcnt(0)" ::: "memory");
    __builtin_amdgcn_sched_barrier(0);
    __builtin_amdgcn_s_barrier();
    if (t + 2 < nt)
      stage64(A, lda, B, ldb, (t + 2) * 64, As + cur * 8192, Bs + cur * 8192,
              wv, ln, srow, scol);
    // (c) MFMAs read registers only; overlap the in-flight prefetch loads.
#pragma unroll
    for (int dk = 0; dk < 2; ++dk)
#pragma unroll
      for (int i = 0; i < 4; ++i)
#pragma unroll
        for (int j = 0; j < 4; ++j)
          acc[i][j] = __builtin_amdgcn_mfma_f32_16x16x32_bf16(a[dk][i], b[dk][j],
                                                              acc[i][j], 0, 0, 0);
  }
}

// ---------------------------------------------------------------------------
// Fused QKV projection: Y[m, 0:2304] = x[m,:] @ [Wq;Wk;Wv]^T + [bq;bk;bv]
// Epilogues write attention-friendly layouts:
//   q2[h][i][r*64+d]  (K-contiguous for QK^T, scaled)
//   k2[h][j][r*64+d]
//   v3[h][r*64+d][j]  (K-contiguous for PV)
// XCD-bijective swizzle: nwg=4608=8*576; same-m0 blocks stay on one XCD.
// ---------------------------------------------------------------------------
__global__ __launch_bounds__(256) void qkv_proj(
    const unsigned short* __restrict__ A, const unsigned short* __restrict__ B,
    const float* __restrict__ bq, const float* __restrict__ bk,
    const float* __restrict__ bv, unsigned short* __restrict__ q2,
    unsigned short* __restrict__ k2, unsigned short* __restrict__ v3, float scaling) {
  __shared__ unsigned short As[2 * 128 * 64];
  __shared__ unsigned short Bs[2 * 128 * 64];
  const int tid = threadIdx.x, wv = tid >> 6, ln = tid & 63;
  const unsigned p = blockIdx.x + blockIdx.y * 18;
  const unsigned l = (p & 7) * 576 + (p >> 3);
  const int bx = l % 18, by = l / 18;
  const int n0 = bx * 128, m0 = by * 128;
  const int wm = (wv & 1) * 64, wn = (wv >> 1) * 64;
  f32x4 acc[4][4] = {};
  gemm128(A + (size_t)m0 * 768, 768, B + (size_t)n0 * 768, 768, 768,
          As, Bs, wv, ln, wm, wn, acc);

  const int region = bx / 6;                       // 0=q, 1=k, 2=v (128 | 768)
  const float* bias = region == 0 ? bq : (region == 1 ? bk : bv);
  const float sc = region == 0 ? scaling : 1.0f;
  const int nq0 = n0 - region * 768;               // within-region base
#pragma unroll
  for (int j = 0; j < 4; ++j) {
    const int np = nq0 + wn + j * 16 + (ln & 15);  // [0,768): same h for 16-lane grp
    const int h = np >> 6, d = np & 63;
    const float bn = bias[np];
#pragma unroll
    for (int i = 0; i < 4; ++i) {
      const int mb = m0 + wm + i * 16 + (ln >> 4) * 4;  // token base, 4 consecutive
      if (region < 2) {
        unsigned short* dst = region == 0 ? q2 : k2;
#pragma unroll
        for (int r = 0; r < 4; ++r) {
          const int m = mb + r;
          const int ic = m & 255, rr = m >> 8;     // token = rr*256 + ic
          dst[(size_t)h * 2097152 + (size_t)ic * 8192 + rr * 64 + d] =
              f2b((acc[i][j][r] + bn) * sc);
        }
      } else {
        const int jc = mb & 255, rr = mb >> 8;     // 4 consecutive j-cols, same rr
        ushort4v o;
#pragma unroll
        for (int r = 0; r < 4; ++r) o[r] = f2b(acc[i][j][r] + bn);
        *(ushort4v*)(v3 + (size_t)h * 2097152 + ((size_t)rr * 64 + d) * 256 + jc) = o;
      }
    }
  }
}

// ---------------------------------------------------------------------------
// QK^T: per head, S[i,j] = sum_{rd} q2[h][i][rd] * k2[h][j][rd]; K=8192 split 8x.
// grid (4, 12, 8): bx -> 2x2 (i,j) 128-tiles, y = head, z = K-chunk of 1024.
// ---------------------------------------------------------------------------
__global__ __launch_bounds__(256) void qk_gemm(const unsigned short* __restrict__ q2,
                                               const unsigned short* __restrict__ k2,
                                               float* __restrict__ Sp) {
  __shared__ unsigned short As[2 * 128 * 64];
  __shared__ unsigned short Bs[2 * 128 * 64];
  const int tid = threadIdx.x, wv = tid >> 6, ln = tid & 63;
  const int i0 = (blockIdx.x & 1) * 128, j0 = (blockIdx.x >> 1) * 128;
  const int h = blockIdx.y, kc = blockIdx.z;
  const int wm = (wv & 1) * 64, wn = (wv >> 1) * 64;
  f32x4 acc[4][4] = {};
  const unsigned short* Ap = q2 + (size_t)h * 2097152 + (size_t)i0 * 8192 + kc * 1024;
  const unsigned short* Bp = k2 + (size_t)h * 2097152 + (size_t)j0 * 8192 + kc * 1024;
  gemm128(Ap, 8192, Bp, 8192, 1024, As, Bs, wv, ln, wm, wn, acc);
  float* out = Sp + ((size_t)kc * H + h) * 65536;
#pragma unroll
  for (int j = 0; j < 4; ++j) {
    const int jj = j0 + wn + j * 16 + (ln & 15);
#pragma unroll
    for (int i = 0; i < 4; ++i)
#pragma unroll
      for (int r = 0; r < 4; ++r) {
        const int ii = i0 + wm + i * 16 + (ln >> 4) * 4 + r;
        out[(size_t)ii * 256 + jj] = acc[i][j][r];
      }
  }
}

// ---------------------------------------------------------------------------
// Sum 8 K-partials, softmax over j, write fp32 probs (d_out) + bf16 copy (ws).
// ---------------------------------------------------------------------------
__global__ __launch_bounds__(256) void softmax_k(const float* __restrict__ Sp,
                                                 float* __restrict__ P,
                                                 unsigned short* __restrict__ Pb) {
  const int row = blockIdx.x, j = threadIdx.x;  // row = h*C + i
  const size_t stride = (size_t)H * Cc * Cc;    // 786432
  const size_t base = (size_t)row * Cc + j;
  float s = 0.f;
#pragma unroll
  for (int c = 0; c < 8; ++c) s += Sp[base + c * stride];
  float m = s;
#pragma unroll
  for (int o = 32; o > 0; o >>= 1) m = fmaxf(m, __shfl_xor(m, o));
  __shared__ float sm[4], ss[4];
  const int wid = j >> 6, lane = j & 63;
  if (lane == 0) sm[wid] = m;
  __syncthreads();
  m = fmaxf(fmaxf(sm[0], sm[1]), fmaxf(sm[2], sm[3]));
  float e = expf(s - m);
  float t = e;
#pragma unroll
  for (int o = 32; o > 0; o >>= 1) t += __shfl_xor(t, o);
  if (lane == 0) ss[wid] = t;
  __syncthreads();
  t = ss[0] + ss[1] + ss[2] + ss[3];
  const float p = e / t;
  P[base] = p;
  Pb[base] = f2b(p);
}

// ---------------------------------------------------------------------------
// PV: per head, C2[i][rd] = sum_j P[h][i][j] * v3[h][rd][j]  (M=256,N=8192,K=256)
// grid (128, 12): bx -> 2 (i) x 64 (rd) 128-tiles, y = head. Epilogue scatters
// straight to token layout Co[(r*256+i)*768 + h*64 + d] for the O-projection.
// ---------------------------------------------------------------------------
__global__ __launch_bounds__(256) void pv_gemm(const unsigned short* __restrict__ P,
                                               const unsigned short* __restrict__ V,
                                               unsigned short* __restrict__ Co) {
  __shared__ unsigned short As[2 * 128 * 64];
  __shared__ unsigned short Bs[2 * 128 * 64];
  const int tid = threadIdx.x, wv = tid >> 6, ln = tid & 63;
  const unsigned p = blockIdx.x + blockIdx.y * 128;
  const unsigned l = (p & 7) * 192 + (p >> 3);     // nwg = 1536 = 8*192
  const int bx = l & 127, h = l >> 7;
  const int i0 = (bx & 1) * 128, n0 = (bx >> 1) * 128;
  const int wm = (wv & 1) * 64, wn = (wv >> 1) * 64;
  f32x4 acc[4][4] = {};
  const unsigned short* Ap = P + (size_t)h * 65536 + (size_t)i0 * 256;
  const unsigned short* Bp = V + (size_t)h * 2097152 + (size_t)n0 * 256;
  gemm128(Ap, 256, Bp, 256, 256, As, Bs, wv, ln, wm, wn, acc);
#pragma unroll
  for (int j = 0; j < 4; ++j) {
    const int n = n0 + wn + j * 16 + (ln & 15);    // rd; same rr for 16-lane grp
    const int rr = n >> 6, d = n & 63;
#pragma unroll
    for (int i = 0; i < 4; ++i)
#pragma unroll
      for (int r = 0; r < 4; ++r) {
        const int ii = i0 + wm + i * 16 + (ln >> 4) * 4 + r;
        Co[((size_t)rr * 256 + ii) * 768 + h * 64 + d] = f2b(acc[i][j][r]);
      }
  }
}

// ---------------------------------------------------------------------------
// Output projection: out = Co @ Wo^T + bo (fp32 out), XCD-swizzled.
// ---------------------------------------------------------------------------
__global__ __launch_bounds__(256) void o_proj(const unsigned short* __restrict__ A,
                                              const unsigned short* __restrict__ B,
                                              const float* __restrict__ bias,
                                              float* __restrict__ Y) {
  __shared__ unsigned short As[2 * 128 * 64];
  __shared__ unsigned short Bs[2 * 128 * 64];
  const int tid = threadIdx.x, wv = tid >> 6, ln = tid & 63;
  const unsigned p = blockIdx.x + blockIdx.y * 6;
  const unsigned l = (p & 7) * 192 + (p >> 3);     // nwg = 1536 = 8*192
  const int bx = l % 6, by = l / 6;
  const int n0 = bx * 128, m0 = by * 128;
  const int wm = (wv & 1) * 64, wn = (wv >> 1) * 64;
  f32x4 acc[4][4] = {};
  gemm128(A + (size_t)m0 * 768, 768, B + (size_t)n0 * 768, 768, 768,
          As, Bs, wv, ln, wm, wn, acc);
#pragma unroll
  for (int j = 0; j < 4; ++j) {
    const int n = n0 + wn + j * 16 + (ln & 15);
    const float bn = bias[n];
#pragma unroll
    for (int i = 0; i < 4; ++i)
#pragma unroll
      for (int r = 0; r < 4; ++r) {
        const int m = m0 + wm + i * 16 + (ln >> 4) * 4 + r;
        Y[(size_t)m * 768 + n] = acc[i][j][r] + bn;
      }
  }
}

// ---------------------------------------------------------------------------
extern "C" void kernel_launch(void* const* d_in, const int* in_sizes, int n_in,
                              void* d_out, int out_size, void* d_ws, size_t ws_size,
                              hipStream_t stream) {
  const float* x  = (const float*)d_in[0];
  const float* Wq = (const float*)d_in[1];
  const float* bq = (const float*)d_in[2];
  const float* Wk = (const float*)d_in[3];
  const float* bk = (const float*)d_in[4];
  const float* Wv = (const float*)d_in[5];
  const float* bv = (const float*)d_in[6];
  const float* Wo = (const float*)d_in[7];
  const float* bo = (const float*)d_in[8];
  float* out = (float*)d_out;             // (R,C,1,E)
  float* probs = out + TOK;               // (H,1,C,C)

  char* ws = (char*)d_ws;
  unsigned short* x_bf  = (unsigned short*)(ws);              // 50.3 MB (dead after qkv_proj)
  unsigned short* q2    = (unsigned short*)(ws + 50331648);   // 50.3 MB [h][i][rd]
  unsigned short* k2    = (unsigned short*)(ws + 100663296);  // 50.3 MB [h][j][rd]
  unsigned short* v3    = (unsigned short*)(ws + 150994944);  // 50.3 MB [h][rd][j]
  unsigned short* Wq_bf = (unsigned short*)(ws + 201326592);  // 4 x 1.18 MB (contiguous!)
  unsigned short* Wk_bf = Wq_bf + 589824;
  unsigned short* Wv_bf = Wk_bf + 589824;
  unsigned short* Wo_bf = Wv_bf + 589824;
  // aliases into dead x_bf region:
  float* S_part         = (float*)(ws);                       // 8 x 3.15 MB = 25.2 MB
  unsigned short* P_bf  = (unsigned short*)(ws + 25165824);   // 1.6 MB
  unsigned short* c_bf  = q2;  // q2 dead after qk_gemm

  const float scaling = 0.125f / sqrtf(128.f);  // Dk^-0.5 / sqrt(R)

  cvt_bf16<<<12288, 256, 0, stream>>>(x, x_bf, 3145728);
  cvt_bf16<<<288, 256, 0, stream>>>(Wq, Wq_bf, 73728);
  cvt_bf16<<<288, 256, 0, stream>>>(Wk, Wk_bf, 73728);
  cvt_bf16<<<288, 256, 0, stream>>>(Wv, Wv_bf, 73728);
  cvt_bf16<<<288, 256, 0, stream>>>(Wo, Wo_bf, 73728);

  // Fused QKV: N = 2304 (Wq,Wk,Wv contiguous rows), x fetched once.
  qkv_proj<<<dim3(18, 256), 256, 0, stream>>>(x_bf, Wq_bf, bq, bk, bv,
                                              q2, k2, v3, scaling);

  qk_gemm<<<dim3(4, H, 8), 256, 0, stream>>>(q2, k2, S_part);
  softmax_k<<<H * Cc, 256, 0, stream>>>(S_part, probs, P_bf);
  pv_gemm<<<dim3(128, H), 256, 0, stream>>>(P_bf, v3, c_bf);

  o_proj<<<dim3(6, 256), 256, 0, stream>>>(c_bf, Wo_bf, bo, out);
}